// Round 2
// baseline (635.285 us; speedup 1.0000x reference)
//
#include <hip/hip_runtime.h>
#include <hip/hip_bf16.h>
#include <math.h>

// GNNConv: out = leaky(segsum_dst(leaky([pos_j-pos_i+delta_i, x_j] @ f_w + f_b)) @ g_w1 + g_b1) @ g_w2 + g_b2 + x
// Algebraic rewrite: msg_in @ f_w = rel @ f_w[0:3] + x[src] @ f_w[3:]
//   -> per-NODE Yb = x @ f_w[3:] + f_b (1.64 GF) instead of per-EDGE (26.8 GF).
// Workspace budget: only delta[N*3] + Yb[N*128] = 26.2 MB; aggr lives in d_out.

#define LEAKY(v) ((v) >= 0.0f ? (v) : 0.01f * (v))

// ---------------- Tiled node GEMM: out[n,j] = epilogue(sum_k A[n,k] W[k,j]) ----------------
// A: [N,128] row-major, W: [128,128] row-major, bias: [128]
__global__ __launch_bounds__(256) void gemm_node(
    const float* __restrict__ A,
    const float* __restrict__ W,
    const float* __restrict__ bias,
    const float* __restrict__ residual,
    float* __restrict__ out,
    int N, int do_leaky)
{
    __shared__ float As[16][132];   // [k][n] transposed, padded
    __shared__ float Ws[16][128];   // [k][j]

    const int tid = threadIdx.x;
    const int bn  = blockIdx.x * 128;
    const int tx  = tid & 15;       // col group (8 cols each)
    const int ty  = tid >> 4;       // row group (8 rows each)

    float acc[8][8];
    #pragma unroll
    for (int i = 0; i < 8; ++i)
        #pragma unroll
        for (int j = 0; j < 8; ++j) acc[i][j] = 0.0f;

    #pragma unroll 1
    for (int k0 = 0; k0 < 128; k0 += 16) {
        {
            const int n  = tid >> 2;          // 0..63
            const int kq = (tid & 3) * 4;     // 0,4,8,12
            #pragma unroll
            for (int h = 0; h < 2; ++h) {
                const int nn  = n + h * 64;
                const int row = bn + nn;
                float4 v = make_float4(0.f, 0.f, 0.f, 0.f);
                if (row < N) v = *(const float4*)(A + (size_t)row * 128 + k0 + kq);
                As[kq + 0][nn] = v.x;
                As[kq + 1][nn] = v.y;
                As[kq + 2][nn] = v.z;
                As[kq + 3][nn] = v.w;
            }
        }
        {
            const int k = tid >> 4;           // 0..15
            const int j = (tid & 15) * 8;     // 0..120
            const float* wp = W + (size_t)(k0 + k) * 128 + j;
            *(float4*)&Ws[k][j]     = *(const float4*)(wp);
            *(float4*)&Ws[k][j + 4] = *(const float4*)(wp + 4);
        }
        __syncthreads();

        #pragma unroll
        for (int kk = 0; kk < 16; ++kk) {
            float a[8], w[8];
            *(float4*)&a[0] = *(float4*)&As[kk][ty * 8];
            *(float4*)&a[4] = *(float4*)&As[kk][ty * 8 + 4];
            *(float4*)&w[0] = *(float4*)&Ws[kk][tx * 8];
            *(float4*)&w[4] = *(float4*)&Ws[kk][tx * 8 + 4];
            #pragma unroll
            for (int i = 0; i < 8; ++i)
                #pragma unroll
                for (int j = 0; j < 8; ++j)
                    acc[i][j] += a[i] * w[j];
        }
        __syncthreads();
    }

    #pragma unroll
    for (int i = 0; i < 8; ++i) {
        const int row = bn + ty * 8 + i;
        if (row >= N) continue;
        const size_t base = (size_t)row * 128;
        #pragma unroll
        for (int j0 = 0; j0 < 8; j0 += 4) {
            const int col = tx * 8 + j0;
            const float4 b = *(const float4*)(bias + col);
            float4 v;
            v.x = acc[i][j0 + 0] + b.x;
            v.y = acc[i][j0 + 1] + b.y;
            v.z = acc[i][j0 + 2] + b.z;
            v.w = acc[i][j0 + 3] + b.w;
            if (do_leaky) {
                v.x = LEAKY(v.x); v.y = LEAKY(v.y);
                v.z = LEAKY(v.z); v.w = LEAKY(v.w);
            }
            if (residual) {
                const float4 r = *(const float4*)(residual + base + col);
                v.x += r.x; v.y += r.y; v.z += r.z; v.w += r.w;
            }
            *(float4*)(out + base + col) = v;
        }
    }
}

// ---------------- fused: delta = tanh(leaky(x @ h_w1 + h_b1) @ h_w2 + h_b2) ----------------
// 128-node tile per block; hidden tile kept in registers, reduced to [128,3] via LDS.
__global__ __launch_bounds__(256) void delta_fused(
    const float* __restrict__ x,
    const float* __restrict__ h_w1,   // [128,128]
    const float* __restrict__ h_b1,   // [128]
    const float* __restrict__ h_w2,   // [128,3]
    const float* __restrict__ h_b2,   // [3]
    float* __restrict__ delta,        // [N,3]
    int N)
{
    __shared__ float As[16][132];
    __shared__ float Ws[16][128];
    __shared__ float W2s[128][3];
    __shared__ float red[128][3];

    const int tid = threadIdx.x;
    const int bn  = blockIdx.x * 128;
    const int tx  = tid & 15;
    const int ty  = tid >> 4;

    if (tid < 128) {
        W2s[tid][0] = h_w2[tid * 3 + 0];
        W2s[tid][1] = h_w2[tid * 3 + 1];
        W2s[tid][2] = h_w2[tid * 3 + 2];
        red[tid][0] = 0.f; red[tid][1] = 0.f; red[tid][2] = 0.f;
    }

    float acc[8][8];
    #pragma unroll
    for (int i = 0; i < 8; ++i)
        #pragma unroll
        for (int j = 0; j < 8; ++j) acc[i][j] = 0.0f;

    #pragma unroll 1
    for (int k0 = 0; k0 < 128; k0 += 16) {
        {
            const int n  = tid >> 2;
            const int kq = (tid & 3) * 4;
            #pragma unroll
            for (int h = 0; h < 2; ++h) {
                const int nn  = n + h * 64;
                const int row = bn + nn;
                float4 v = make_float4(0.f, 0.f, 0.f, 0.f);
                if (row < N) v = *(const float4*)(x + (size_t)row * 128 + k0 + kq);
                As[kq + 0][nn] = v.x;
                As[kq + 1][nn] = v.y;
                As[kq + 2][nn] = v.z;
                As[kq + 3][nn] = v.w;
            }
        }
        {
            const int k = tid >> 4;
            const int j = (tid & 15) * 8;
            const float* wp = h_w1 + (size_t)(k0 + k) * 128 + j;
            *(float4*)&Ws[k][j]     = *(const float4*)(wp);
            *(float4*)&Ws[k][j + 4] = *(const float4*)(wp + 4);
        }
        __syncthreads();

        #pragma unroll
        for (int kk = 0; kk < 16; ++kk) {
            float a[8], w[8];
            *(float4*)&a[0] = *(float4*)&As[kk][ty * 8];
            *(float4*)&a[4] = *(float4*)&As[kk][ty * 8 + 4];
            *(float4*)&w[0] = *(float4*)&Ws[kk][tx * 8];
            *(float4*)&w[4] = *(float4*)&Ws[kk][tx * 8 + 4];
            #pragma unroll
            for (int i = 0; i < 8; ++i)
                #pragma unroll
                for (int j = 0; j < 8; ++j)
                    acc[i][j] += a[i] * w[j];
        }
        __syncthreads();
    }

    // hidden = leaky(acc + b1); partial dot with h_w2 -> LDS reduce
    #pragma unroll
    for (int i = 0; i < 8; ++i) {
        float p0 = 0.f, p1 = 0.f, p2 = 0.f;
        #pragma unroll
        for (int jj = 0; jj < 8; ++jj) {
            const int col = tx * 8 + jj;
            float h = acc[i][jj] + h_b1[col];
            h = LEAKY(h);
            p0 += h * W2s[col][0];
            p1 += h * W2s[col][1];
            p2 += h * W2s[col][2];
        }
        const int rl = ty * 8 + i;
        atomicAdd(&red[rl][0], p0);
        atomicAdd(&red[rl][1], p1);
        atomicAdd(&red[rl][2], p2);
    }
    __syncthreads();

    if (tid < 128) {
        const int row = bn + tid;
        if (row < N) {
            delta[(size_t)row * 3 + 0] = tanhf(red[tid][0] + h_b2[0]);
            delta[(size_t)row * 3 + 1] = tanhf(red[tid][1] + h_b2[1]);
            delta[(size_t)row * 3 + 2] = tanhf(red[tid][2] + h_b2[2]);
        }
    }
}

// ---------------- edge kernel: aggr[dst] += leaky(Yb[src] + rel @ f_w[0:3]) ----------------
__global__ __launch_bounds__(256) void edge_kernel(
    const int* __restrict__ ei,        // [2,E]: src = ei[0:E], dst = ei[E:2E]
    const float* __restrict__ pos,     // [N,3]
    const float* __restrict__ delta,   // [N,3]
    const float* __restrict__ Yb,      // [N,128]
    const float* __restrict__ fw3,     // f_w rows 0..2 -> [3][128]
    float* __restrict__ aggr,          // [N,128]  (= d_out)
    int E)
{
    const int le = threadIdx.x >> 7;   // local edge 0/1
    const int c  = threadIdx.x & 127;  // channel
    const long e = (long)blockIdx.x * 2 + le;
    const bool valid = (e < E);

    int src = 0, dst = 0;
    if (valid) {
        src = ei[e];
        dst = ei[(size_t)E + e];
    }

    __shared__ float rels[2][3];
    if (valid && c < 3) {
        rels[le][c] = pos[(size_t)src * 3 + c] - pos[(size_t)dst * 3 + c]
                    + delta[(size_t)dst * 3 + c];
    }
    __syncthreads();

    if (valid) {
        const float r0 = rels[le][0], r1 = rels[le][1], r2 = rels[le][2];
        float z = Yb[(size_t)src * 128 + c]
                + r0 * fw3[c] + r1 * fw3[128 + c] + r2 * fw3[256 + c];
        z = LEAKY(z);
        atomicAdd(&aggr[(size_t)dst * 128 + c], z);
    }
}

// ---------------- launch ----------------
extern "C" void kernel_launch(void* const* d_in, const int* in_sizes, int n_in,
                              void* d_out, int out_size, void* d_ws, size_t ws_size,
                              hipStream_t stream) {
    const float* x    = (const float*)d_in[0];
    const float* pos  = (const float*)d_in[1];
    const int*   ei   = (const int*)d_in[2];   // harness stages integer inputs as int32
    const float* h_w1 = (const float*)d_in[3];
    const float* h_b1 = (const float*)d_in[4];
    const float* h_w2 = (const float*)d_in[5];
    const float* h_b2 = (const float*)d_in[6];
    const float* f_w  = (const float*)d_in[7];   // [131,128]
    const float* f_b  = (const float*)d_in[8];
    const float* g_w1 = (const float*)d_in[9];
    const float* g_b1 = (const float*)d_in[10];
    const float* g_w2 = (const float*)d_in[11];
    const float* g_b2 = (const float*)d_in[12];
    float* out = (float*)d_out;

    const int N = in_sizes[0] / 128;
    const int E = in_sizes[2] / 2;

    // workspace (26.2 MB): delta [N*3] | Yb [N*128].  aggr lives in d_out; hg reuses Yb.
    float* delta = (float*)d_ws;
    float* Yb    = delta + (size_t)N * 3;
    float* aggr  = out;
    float* hg    = Yb;   // dead after edge_kernel

    const int gemm_blocks = (N + 127) / 128;

    // 1. zero the aggregation buffer (d_out is poisoned each launch)
    hipMemsetAsync(aggr, 0, (size_t)N * 128 * sizeof(float), stream);

    // 2. delta = tanh(leaky(x@h_w1+h_b1)@h_w2 + h_b2)   (fused, no hidden buffer)
    delta_fused<<<gemm_blocks, 256, 0, stream>>>(x, h_w1, h_b1, h_w2, h_b2, delta, N);

    // 3. Yb = x @ f_w[3:] + f_b
    gemm_node<<<gemm_blocks, 256, 0, stream>>>(x, f_w + 3 * 128, f_b, nullptr, Yb, N, 0);

    // 4. edge messages + scatter-add into d_out
    edge_kernel<<<(E + 1) / 2, 256, 0, stream>>>(ei, pos, delta, Yb, f_w, aggr, E);

    // 5. hg = leaky(aggr @ g_w1 + g_b1)      (aggr = d_out -> hg = Yb buffer)
    gemm_node<<<gemm_blocks, 256, 0, stream>>>(aggr, g_w1, g_b1, nullptr, hg, N, 1);

    // 6. out = hg @ g_w2 + g_b2 + x
    gemm_node<<<gemm_blocks, 256, 0, stream>>>(hg, g_w2, g_b2, x, out, N, 0);
}

// Round 3
// 424.890 us; speedup vs baseline: 1.4952x; 1.4952x over previous
//
#include <hip/hip_runtime.h>
#include <hip/hip_bf16.h>
#include <math.h>

// GNNConv: out = leaky(segsum_dst(leaky([pos_j-pos_i+delta_i, x_j] @ f_w + f_b)) @ g_w1 + g_b1) @ g_w2 + g_b2 + x
// Rewrites:
//  (1) msg @ f_w = rel @ f_w[0:3] + x[src] @ f_w[3:]  -> per-node Yb instead of per-edge GEMM.
//  (2) dst-sorted aggregation (counting sort on device) -> register accumulation, one write
//      per aggr row, ZERO fp32 atomics (round-2 profile: 400 MB atomic write-through was 62% of time).

#define LEAKY(v) ((v) >= 0.0f ? (v) : 0.01f * (v))

// ---------------- Tiled node GEMM: out[n,j] = epilogue(sum_k A[n,k] W[k,j]) ----------------
__global__ __launch_bounds__(256) void gemm_node(
    const float* __restrict__ A,
    const float* __restrict__ W,
    const float* __restrict__ bias,
    const float* __restrict__ residual,
    float* __restrict__ out,
    int N, int do_leaky)
{
    __shared__ float As[16][132];
    __shared__ float Ws[16][128];

    const int tid = threadIdx.x;
    const int bn  = blockIdx.x * 128;
    const int tx  = tid & 15;
    const int ty  = tid >> 4;

    float acc[8][8];
    #pragma unroll
    for (int i = 0; i < 8; ++i)
        #pragma unroll
        for (int j = 0; j < 8; ++j) acc[i][j] = 0.0f;

    #pragma unroll 1
    for (int k0 = 0; k0 < 128; k0 += 16) {
        {
            const int n  = tid >> 2;
            const int kq = (tid & 3) * 4;
            #pragma unroll
            for (int h = 0; h < 2; ++h) {
                const int nn  = n + h * 64;
                const int row = bn + nn;
                float4 v = make_float4(0.f, 0.f, 0.f, 0.f);
                if (row < N) v = *(const float4*)(A + (size_t)row * 128 + k0 + kq);
                As[kq + 0][nn] = v.x;
                As[kq + 1][nn] = v.y;
                As[kq + 2][nn] = v.z;
                As[kq + 3][nn] = v.w;
            }
        }
        {
            const int k = tid >> 4;
            const int j = (tid & 15) * 8;
            const float* wp = W + (size_t)(k0 + k) * 128 + j;
            *(float4*)&Ws[k][j]     = *(const float4*)(wp);
            *(float4*)&Ws[k][j + 4] = *(const float4*)(wp + 4);
        }
        __syncthreads();

        #pragma unroll
        for (int kk = 0; kk < 16; ++kk) {
            float a[8], w[8];
            *(float4*)&a[0] = *(float4*)&As[kk][ty * 8];
            *(float4*)&a[4] = *(float4*)&As[kk][ty * 8 + 4];
            *(float4*)&w[0] = *(float4*)&Ws[kk][tx * 8];
            *(float4*)&w[4] = *(float4*)&Ws[kk][tx * 8 + 4];
            #pragma unroll
            for (int i = 0; i < 8; ++i)
                #pragma unroll
                for (int j = 0; j < 8; ++j)
                    acc[i][j] += a[i] * w[j];
        }
        __syncthreads();
    }

    #pragma unroll
    for (int i = 0; i < 8; ++i) {
        const int row = bn + ty * 8 + i;
        if (row >= N) continue;
        const size_t base = (size_t)row * 128;
        #pragma unroll
        for (int j0 = 0; j0 < 8; j0 += 4) {
            const int col = tx * 8 + j0;
            const float4 b = *(const float4*)(bias + col);
            float4 v;
            v.x = acc[i][j0 + 0] + b.x;
            v.y = acc[i][j0 + 1] + b.y;
            v.z = acc[i][j0 + 2] + b.z;
            v.w = acc[i][j0 + 3] + b.w;
            if (do_leaky) {
                v.x = LEAKY(v.x); v.y = LEAKY(v.y);
                v.z = LEAKY(v.z); v.w = LEAKY(v.w);
            }
            if (residual) {
                const float4 r = *(const float4*)(residual + base + col);
                v.x += r.x; v.y += r.y; v.z += r.z; v.w += r.w;
            }
            *(float4*)(out + base + col) = v;
        }
    }
}

// ---------------- fused: delta = tanh(leaky(x @ h_w1 + h_b1) @ h_w2 + h_b2) ----------------
__global__ __launch_bounds__(256) void delta_fused(
    const float* __restrict__ x,
    const float* __restrict__ h_w1,
    const float* __restrict__ h_b1,
    const float* __restrict__ h_w2,   // [128,3]
    const float* __restrict__ h_b2,   // [3]
    float* __restrict__ delta,        // [N,3]
    int N)
{
    __shared__ float As[16][132];
    __shared__ float Ws[16][128];
    __shared__ float W2s[128][3];
    __shared__ float red[128][3];

    const int tid = threadIdx.x;
    const int bn  = blockIdx.x * 128;
    const int tx  = tid & 15;
    const int ty  = tid >> 4;

    if (tid < 128) {
        W2s[tid][0] = h_w2[tid * 3 + 0];
        W2s[tid][1] = h_w2[tid * 3 + 1];
        W2s[tid][2] = h_w2[tid * 3 + 2];
        red[tid][0] = 0.f; red[tid][1] = 0.f; red[tid][2] = 0.f;
    }

    float acc[8][8];
    #pragma unroll
    for (int i = 0; i < 8; ++i)
        #pragma unroll
        for (int j = 0; j < 8; ++j) acc[i][j] = 0.0f;

    #pragma unroll 1
    for (int k0 = 0; k0 < 128; k0 += 16) {
        {
            const int n  = tid >> 2;
            const int kq = (tid & 3) * 4;
            #pragma unroll
            for (int h = 0; h < 2; ++h) {
                const int nn  = n + h * 64;
                const int row = bn + nn;
                float4 v = make_float4(0.f, 0.f, 0.f, 0.f);
                if (row < N) v = *(const float4*)(x + (size_t)row * 128 + k0 + kq);
                As[kq + 0][nn] = v.x;
                As[kq + 1][nn] = v.y;
                As[kq + 2][nn] = v.z;
                As[kq + 3][nn] = v.w;
            }
        }
        {
            const int k = tid >> 4;
            const int j = (tid & 15) * 8;
            const float* wp = h_w1 + (size_t)(k0 + k) * 128 + j;
            *(float4*)&Ws[k][j]     = *(const float4*)(wp);
            *(float4*)&Ws[k][j + 4] = *(const float4*)(wp + 4);
        }
        __syncthreads();

        #pragma unroll
        for (int kk = 0; kk < 16; ++kk) {
            float a[8], w[8];
            *(float4*)&a[0] = *(float4*)&As[kk][ty * 8];
            *(float4*)&a[4] = *(float4*)&As[kk][ty * 8 + 4];
            *(float4*)&w[0] = *(float4*)&Ws[kk][tx * 8];
            *(float4*)&w[4] = *(float4*)&Ws[kk][tx * 8 + 4];
            #pragma unroll
            for (int i = 0; i < 8; ++i)
                #pragma unroll
                for (int j = 0; j < 8; ++j)
                    acc[i][j] += a[i] * w[j];
        }
        __syncthreads();
    }

    #pragma unroll
    for (int i = 0; i < 8; ++i) {
        float p0 = 0.f, p1 = 0.f, p2 = 0.f;
        #pragma unroll
        for (int jj = 0; jj < 8; ++jj) {
            const int col = tx * 8 + jj;
            float h = acc[i][jj] + h_b1[col];
            h = LEAKY(h);
            p0 += h * W2s[col][0];
            p1 += h * W2s[col][1];
            p2 += h * W2s[col][2];
        }
        const int rl = ty * 8 + i;
        atomicAdd(&red[rl][0], p0);
        atomicAdd(&red[rl][1], p1);
        atomicAdd(&red[rl][2], p2);
    }
    __syncthreads();

    if (tid < 128) {
        const int row = bn + tid;
        if (row < N) {
            delta[(size_t)row * 3 + 0] = tanhf(red[tid][0] + h_b2[0]);
            delta[(size_t)row * 3 + 1] = tanhf(red[tid][1] + h_b2[1]);
            delta[(size_t)row * 3 + 2] = tanhf(red[tid][2] + h_b2[2]);
        }
    }
}

// ---------------- counting sort of edges by dst ----------------
__global__ __launch_bounds__(256) void hist_kernel(
    const int* __restrict__ ei, int* __restrict__ counts, int E)
{
    const int e = blockIdx.x * 256 + threadIdx.x;
    if (e < E) atomicAdd(&counts[ei[(size_t)E + e]], 1);
}

// block-local exclusive scan over 1024 elements; emits block total.
__global__ __launch_bounds__(256) void scan_local(
    const int* __restrict__ counts, int* __restrict__ offs,
    int* __restrict__ blocksums, int N)
{
    __shared__ int s[256];
    const int tid  = threadIdx.x;
    const int base = blockIdx.x * 1024 + tid * 4;
    int v[4], sum = 0;
    #pragma unroll
    for (int j = 0; j < 4; ++j) {
        v[j] = (base + j < N) ? counts[base + j] : 0;
        sum += v[j];
    }
    s[tid] = sum;
    __syncthreads();
    for (int d = 1; d < 256; d <<= 1) {
        int t = (tid >= d) ? s[tid - d] : 0;
        __syncthreads();
        s[tid] += t;
        __syncthreads();
    }
    int run = s[tid] - sum;   // exclusive prefix of this thread's chunk
    #pragma unroll
    for (int j = 0; j < 4; ++j) {
        if (base + j < N) offs[base + j] = run;
        run += v[j];
    }
    if (tid == 255) blocksums[blockIdx.x] = s[255];
}

// single-block exclusive scan of blocksums (B <= 1024)
__global__ __launch_bounds__(256) void scan_top(
    int* __restrict__ blocksums, int B)
{
    __shared__ int s[256];
    const int tid = threadIdx.x;
    int v[4], sum = 0;
    const int base = tid * 4;
    #pragma unroll
    for (int j = 0; j < 4; ++j) {
        v[j] = (base + j < B) ? blocksums[base + j] : 0;
        sum += v[j];
    }
    s[tid] = sum;
    __syncthreads();
    for (int d = 1; d < 256; d <<= 1) {
        int t = (tid >= d) ? s[tid - d] : 0;
        __syncthreads();
        s[tid] += t;
        __syncthreads();
    }
    int run = s[tid] - sum;
    #pragma unroll
    for (int j = 0; j < 4; ++j) {
        if (base + j < B) blocksums[base + j] = run;
        run += v[j];
    }
}

__global__ __launch_bounds__(256) void scan_fixup(
    int* __restrict__ offs, const int* __restrict__ blocksums, int N)
{
    const int i = blockIdx.x * 1024 + threadIdx.x * 4;
    const int add = blocksums[blockIdx.x];
    #pragma unroll
    for (int j = 0; j < 4; ++j)
        if (i + j < N) offs[i + j] += add;
}

// scatter src indices into dst-sorted order; offs becomes "segment end" cursor.
__global__ __launch_bounds__(256) void scatter_kernel(
    const int* __restrict__ ei, int* __restrict__ offs,
    int* __restrict__ srcs_sorted, int E)
{
    const int e = blockIdx.x * 256 + threadIdx.x;
    if (e < E) {
        const int src = ei[e];
        const int dst = ei[(size_t)E + e];
        const int p = atomicAdd(&offs[dst], 1);
        srcs_sorted[p] = src;
    }
}

// ---------------- aggregation: aggr[d] = sum_{e in seg(d)} leaky(Yb[src] + rel @ fw3) -------
// 128 threads = 128 channels; 8 dst nodes per block, register accumulator, one store per row.
__global__ __launch_bounds__(128) void aggregate_kernel(
    const int* __restrict__ srcs_sorted,
    const int* __restrict__ offs_end,   // post-scatter: start + count
    const int* __restrict__ counts,
    const float* __restrict__ pos,      // [N,3]
    const float* __restrict__ delta,    // [N,3]
    const float* __restrict__ Yb,       // [N,128]
    const float* __restrict__ fw3,      // [3][128]
    float* __restrict__ aggr,           // [N,128] = d_out
    int N)
{
    const int c = threadIdx.x;
    const float w0 = fw3[c], w1 = fw3[128 + c], w2 = fw3[256 + c];
    const int dbase = blockIdx.x * 8;

    #pragma unroll 1
    for (int g = 0; g < 8; ++g) {
        const int d = dbase + g;
        if (d >= N) return;
        const int len   = counts[d];
        const int start = offs_end[d] - len;
        const float q0 = delta[(size_t)d * 3 + 0] - pos[(size_t)d * 3 + 0];
        const float q1 = delta[(size_t)d * 3 + 1] - pos[(size_t)d * 3 + 1];
        const float q2 = delta[(size_t)d * 3 + 2] - pos[(size_t)d * 3 + 2];
        float acc = 0.0f;
        #pragma unroll 4
        for (int t = 0; t < len; ++t) {
            const int s = srcs_sorted[start + t];
            const float r0 = pos[(size_t)s * 3 + 0] + q0;
            const float r1 = pos[(size_t)s * 3 + 1] + q1;
            const float r2 = pos[(size_t)s * 3 + 2] + q2;
            float z = Yb[(size_t)s * 128 + c] + r0 * w0 + r1 * w1 + r2 * w2;
            acc += LEAKY(z);
        }
        aggr[(size_t)d * 128 + c] = acc;
    }
}

// ---------------- launch ----------------
extern "C" void kernel_launch(void* const* d_in, const int* in_sizes, int n_in,
                              void* d_out, int out_size, void* d_ws, size_t ws_size,
                              hipStream_t stream) {
    const float* x    = (const float*)d_in[0];
    const float* pos  = (const float*)d_in[1];
    const int*   ei   = (const int*)d_in[2];
    const float* h_w1 = (const float*)d_in[3];
    const float* h_b1 = (const float*)d_in[4];
    const float* h_w2 = (const float*)d_in[5];
    const float* h_b2 = (const float*)d_in[6];
    const float* f_w  = (const float*)d_in[7];   // [131,128]
    const float* f_b  = (const float*)d_in[8];
    const float* g_w1 = (const float*)d_in[9];
    const float* g_b1 = (const float*)d_in[10];
    const float* g_w2 = (const float*)d_in[11];
    const float* g_b2 = (const float*)d_in[12];
    float* out = (float*)d_out;

    const int N = in_sizes[0] / 128;
    const int E = in_sizes[2] / 2;

    // ws layout (29.8 MB): delta[N*3] | Yb[N*128] | counts[N] | offs[N] | blocksums[1024] | srcs_sorted[E]
    float* delta = (float*)d_ws;
    float* Yb    = delta + (size_t)N * 3;
    int* counts  = (int*)(Yb + (size_t)N * 128);
    int* offs    = counts + N;
    int* bsums   = offs + N;
    int* srcs    = bsums + 1024;
    float* aggr  = out;
    float* hg    = Yb;   // Yb dead after aggregation

    const int gemm_blocks = (N + 127) / 128;
    const int B = (N + 1023) / 1024;   // scan blocks (49)

    hipMemsetAsync(counts, 0, (size_t)N * sizeof(int), stream);

    delta_fused<<<gemm_blocks, 256, 0, stream>>>(x, h_w1, h_b1, h_w2, h_b2, delta, N);
    gemm_node<<<gemm_blocks, 256, 0, stream>>>(x, f_w + 3 * 128, f_b, nullptr, Yb, N, 0);

    hist_kernel<<<(E + 255) / 256, 256, 0, stream>>>(ei, counts, E);
    scan_local<<<B, 256, 0, stream>>>(counts, offs, bsums, N);
    scan_top<<<1, 256, 0, stream>>>(bsums, B);
    scan_fixup<<<B, 256, 0, stream>>>(offs, bsums, N);
    scatter_kernel<<<(E + 255) / 256, 256, 0, stream>>>(ei, offs, srcs, E);

    aggregate_kernel<<<(N + 7) / 8, 128, 0, stream>>>(
        srcs, offs, counts, pos, delta, Yb, f_w, aggr, N);

    gemm_node<<<gemm_blocks, 256, 0, stream>>>(aggr, g_w1, g_b1, nullptr, hg, N, 1);
    gemm_node<<<gemm_blocks, 256, 0, stream>>>(hg, g_w2, g_b2, x, out, N, 0);
}